// Round 7
// baseline (166.066 us; speedup 1.0000x reference)
//
#include <hip/hip_runtime.h>
#include <cstdint>
#include <cstddef>

// B=8,S=2048,E=512,FFN=2048,Q=8 -> fc2 GEMM: M=16384, N=512, K=2048.
// Fully fused, zero LDS, zero K-loop barriers.
// R4: fc1-in-MFMA row-permutation trick (fc1 D-frag == fc2 A-frag, b1 exact).
// R5: fragment-ordered weight tiles (contiguous 1-KB wave reads).
// R6: 2 m-tiles/wave (20 MFMA : 10 loads).
// R7: __launch_bounds__(256,2) frees VGPR budget (grid caps occupancy at
//     2 waves/SIMD anyway) + explicit unroll-2 ping-pong with bf prefetch
//     issued AFTER fc2 consumes the buffer (no dup live range, no rotation
//     movs, no vmcnt(0) drain). R6's VGPR=100 proved the compiler never
//     materialized the double buffer.
//
// w2t[nt][kt][nl][quad][e]  (nt<4, kt<64, nl<128, quad<4, e<8) bf16, 2 MiB
// w1t[kt][i][fr][quad][e]   (kt<64, i<2, fr<16, quad<4, e<8)  bf16, 128 KiB

typedef __attribute__((ext_vector_type(8))) short s16x8;
typedef __attribute__((ext_vector_type(4))) float f32x4;

__device__ __forceinline__ unsigned short f2bf(float f) {  // RNE
  unsigned int u = __float_as_uint(f);
  unsigned int r = u + 0x7fffu + ((u >> 16) & 1u);
  return (unsigned short)(r >> 16);
}

// two fp32 -> packed bf16 dword (round-half-up; inputs finite)
__device__ __forceinline__ unsigned pk_bf16(float lo, float hi) {
  unsigned ul = __float_as_uint(lo) + 0x8000u;
  unsigned uh = __float_as_uint(hi) + 0x8000u;
  return __builtin_amdgcn_perm(uh, ul, 0x07060302u);  // [hi16(uh)|hi16(ul)]
}

__device__ __forceinline__ s16x8 u4s(uint4 u) {
  union { uint4 a; s16x8 b; } c; c.a = u; return c.b;
}

// fc1 for one m-tile: aw1/aw2 = permuted W1 rows, bz = z-fragment.
// Returns the fc2 A-operand fragment (relu'd, bf16-packed).
__device__ __forceinline__ s16x8 make_a(s16x8 aw1, s16x8 aw2, s16x8 bz) {
  const f32x4 zero4 = (f32x4){0.f, 0.f, 0.f, 0.f};
  f32x4 p1 = __builtin_amdgcn_mfma_f32_16x16x32_bf16(aw1, bz, zero4, 0, 0, 0);
  f32x4 p2 = __builtin_amdgcn_mfma_f32_16x16x32_bf16(aw2, bz, zero4, 0, 0, 0);
  uint4 u;
  u.x = pk_bf16(fmaxf(p1[0], 0.f), fmaxf(p1[1], 0.f));
  u.y = pk_bf16(fmaxf(p1[2], 0.f), fmaxf(p1[3], 0.f));
  u.z = pk_bf16(fmaxf(p2[0], 0.f), fmaxf(p2[1], 0.f));
  u.w = pk_bf16(fmaxf(p2[2], 0.f), fmaxf(p2[3], 0.f));
  return u4s(u);
}

// ---------------------------------------------------------------------------
// Setup/retile. bid<128: w2 -> w2t. bid>=128 (8 blocks): w1,b1 -> w1t.
// ---------------------------------------------------------------------------
__global__ __launch_bounds__(256) void k_cvt(const float* __restrict__ w2,
                                             const float* __restrict__ w1,
                                             const float* __restrict__ b1,
                                             unsigned short* __restrict__ w2t,
                                             unsigned short* __restrict__ w1t) {
  const int bid = blockIdx.x, t = threadIdx.x;
  if (bid < 128) {
    const int tid = bid * 256 + t;
    const int n = tid >> 6, kt = tid & 63;
    const float* src = w2 + (size_t)n * 2048 + kt * 32;
    unsigned short* dst =
        w2t + ((size_t)(n >> 7) * 64 + kt) * 4096 + (n & 127) * 32;
#pragma unroll
    for (int g = 0; g < 4; ++g) {
      float4 v0 = *(const float4*)(src + g * 8);
      float4 v1 = *(const float4*)(src + g * 8 + 4);
      uint4 p;
      p.x = f2bf(v0.x) | ((unsigned)f2bf(v0.y) << 16);
      p.y = f2bf(v0.z) | ((unsigned)f2bf(v0.w) << 16);
      p.z = f2bf(v1.x) | ((unsigned)f2bf(v1.y) << 16);
      p.w = f2bf(v1.z) | ((unsigned)f2bf(v1.w) << 16);
      *(uint4*)(dst + g * 8) = p;
    }
  } else {
    const int idx = (bid - 128) * 256 + t;  // 0..2047 = kt*32 + i*16 + fr
    const int kt = idx >> 5, rem = idx & 31, i = rem >> 4, fr = rem & 15;
    const int f = kt * 32 + 8 * (fr >> 2) + (fr & 3) + 4 * i;
    const float* wr = w1 + (size_t)f * 8;
    float4 a = *(const float4*)wr;
    float4 b = *(const float4*)(wr + 4);
    uint4 q0;
    q0.x = f2bf(a.x) | ((unsigned)f2bf(a.y) << 16);
    q0.y = f2bf(a.z) | ((unsigned)f2bf(a.w) << 16);
    q0.z = f2bf(b.x) | ((unsigned)f2bf(b.y) << 16);
    q0.w = f2bf(b.z) | ((unsigned)f2bf(b.w) << 16);
    uint4 q1 = {(unsigned)f2bf(b1[f]), 0u, 0u, 0u};
    uint4 zz = {0u, 0u, 0u, 0u};
    unsigned short* dst = w1t + (size_t)idx * 32;
    *(uint4*)dst = q0;
    *(uint4*)(dst + 8) = q1;
    *(uint4*)(dst + 16) = zz;
    *(uint4*)(dst + 24) = zz;
  }
}

// ---------------------------------------------------------------------------
// Fused kernel. Block = 128m x 128n, 4 waves, each 32m x 128n (2 m-tiles).
// Grid = 128 mt * 4 nt = 512 blocks (2/CU, 2 waves/SIMD — grid-limited, so
// VGPRs up to 256 are free: hence __launch_bounds__(256, 2)).
// ---------------------------------------------------------------------------
__global__ __launch_bounds__(256, 2) void k_fused(
    const float* __restrict__ x, const float* __restrict__ ry,
    const unsigned short* __restrict__ w1t, const unsigned short* __restrict__ w2t,
    const float* __restrict__ b2, float* __restrict__ out) {
  const int t = threadIdx.x;
  const int lane = t & 63;
  const int w = t >> 6;
  const int fr = lane & 15;
  const int quad = lane >> 4;
  const int mt = blockIdx.x & 127;
  const int nt = blockIdx.x >> 7;
  const int c0 = nt * 128;
  const int m0 = mt * 128 + w * 32;  // wave's 32-row base

  // ---- z B-fragments (kt-invariant), one per m-tile:
  //   quad0: z[m][0..7]; quad1: {1.0, 0..} (b1 slot); quads 2,3: 0.
  float4 ra = *(const float4*)ry;
  float4 rb = *(const float4*)(ry + 4);
  const float cr0 = __cosf(ra.x), cr1 = __cosf(ra.y), cr2 = __cosf(ra.z),
              cr3 = __cosf(ra.w), cr4 = __cosf(rb.x), cr5 = __cosf(rb.y),
              cr6 = __cosf(rb.z), cr7 = __cosf(rb.w);
  s16x8 bz[2];
#pragma unroll
  for (int i = 0; i < 2; ++i) {
    const float* xr = x + (size_t)(m0 + i * 16 + fr) * 512;
    float4 xa = *(const float4*)xr;
    float4 xb = *(const float4*)(xr + 4);
    unsigned zd0 = f2bf(__cosf(xa.x) * cr0) |
                   ((unsigned)f2bf(__cosf(xa.y) * cr1) << 16);
    unsigned zd1 = f2bf(__cosf(xa.z) * cr2) |
                   ((unsigned)f2bf(__cosf(xa.w) * cr3) << 16);
    unsigned zd2 = f2bf(__cosf(xb.x) * cr4) |
                   ((unsigned)f2bf(__cosf(xb.y) * cr5) << 16);
    unsigned zd3 = f2bf(__cosf(xb.z) * cr6) |
                   ((unsigned)f2bf(__cosf(xb.w) * cr7) << 16);
    uint4 bzu;
    bzu.x = (quad == 0) ? zd0 : ((quad == 1) ? 0x00003F80u : 0u);
    bzu.y = (quad == 0) ? zd1 : 0u;
    bzu.z = (quad == 0) ? zd2 : 0u;
    bzu.w = (quad == 0) ? zd3 : 0u;
    bz[i] = u4s(bzu);
  }

  // fragment-ordered base pointers (contiguous 1-KB wave reads)
  const unsigned short* pW = w1t + fr * 32 + quad * 8;  // + kt*1024
  const unsigned short* pB = w2t + (size_t)nt * 64 * 4096 + fr * 32 + quad * 8;
  // + kt*4096 + j*512

  f32x4 acc[2][8];
#pragma unroll
  for (int i = 0; i < 2; ++i)
#pragma unroll
    for (int j = 0; j < 8; ++j) acc[i][j] = (f32x4){0.f, 0.f, 0.f, 0.f};

  // prologue: buffer A <- kt=0, buffer B <- kt=1
  s16x8 awa1 = *(const s16x8*)pW;
  s16x8 awa2 = *(const s16x8*)(pW + 512);
  s16x8 bfa[8];
#pragma unroll
  for (int j = 0; j < 8; ++j) bfa[j] = *(const s16x8*)(pB + j * 512);
  s16x8 awb1 = *(const s16x8*)(pW + 1024);
  s16x8 awb2 = *(const s16x8*)(pW + 1024 + 512);
  s16x8 bfb[8];
#pragma unroll
  for (int j = 0; j < 8; ++j) bfb[j] = *(const s16x8*)(pB + 4096 + j * 512);

  for (int kt = 0; kt < 64; kt += 2) {
    // clamped prefetch indices (tail reloads in-bounds data, discarded)
    const int k2 = (kt + 2 < 64) ? kt + 2 : 62;
    const int k3 = (kt + 3 < 64) ? kt + 3 : 63;

    // ---- step 1: compute kt from buffer A
    {
      s16x8 af0 = make_a(awa1, awa2, bz[0]);
      s16x8 af1 = make_a(awa1, awa2, bz[1]);
      // aw prefetch kt+2 (awa consumed at MFMA issue above)
      awa1 = *(const s16x8*)(pW + (size_t)k2 * 1024);
      awa2 = *(const s16x8*)(pW + (size_t)k2 * 1024 + 512);
#pragma unroll
      for (int j = 0; j < 8; ++j) {
        acc[0][j] = __builtin_amdgcn_mfma_f32_16x16x32_bf16(af0, bfa[j],
                                                            acc[0][j], 0, 0, 0);
        acc[1][j] = __builtin_amdgcn_mfma_f32_16x16x32_bf16(af1, bfa[j],
                                                            acc[1][j], 0, 0, 0);
      }
      // bf prefetch kt+2 AFTER fc2 consumed bfa — reuses the same registers,
      // consumed one full half-iteration later (~300 cyc prefetch distance)
#pragma unroll
      for (int j = 0; j < 8; ++j)
        bfa[j] = *(const s16x8*)(pB + (size_t)k2 * 4096 + j * 512);
    }

    // ---- step 2: compute kt+1 from buffer B
    {
      s16x8 af0 = make_a(awb1, awb2, bz[0]);
      s16x8 af1 = make_a(awb1, awb2, bz[1]);
      awb1 = *(const s16x8*)(pW + (size_t)k3 * 1024);
      awb2 = *(const s16x8*)(pW + (size_t)k3 * 1024 + 512);
#pragma unroll
      for (int j = 0; j < 8; ++j) {
        acc[0][j] = __builtin_amdgcn_mfma_f32_16x16x32_bf16(af0, bfb[j],
                                                            acc[0][j], 0, 0, 0);
        acc[1][j] = __builtin_amdgcn_mfma_f32_16x16x32_bf16(af1, bfb[j],
                                                            acc[1][j], 0, 0, 0);
      }
#pragma unroll
      for (int j = 0; j < 8; ++j)
        bfb[j] = *(const s16x8*)(pB + (size_t)k3 * 4096 + j * 512);
    }
  }

  // epilogue: fc2 D: lane(fr,quad) holds D[m-local=quad*4+rr][n-local=fr]
  float bias[8];
#pragma unroll
  for (int j = 0; j < 8; ++j) bias[j] = b2[c0 + j * 16 + fr];
#pragma unroll
  for (int i = 0; i < 2; ++i) {
    const int mrow = m0 + i * 16 + quad * 4;
#pragma unroll
    for (int rr = 0; rr < 4; ++rr) {
      float* orow = out + (size_t)(mrow + rr) * 512 + c0;
#pragma unroll
      for (int j = 0; j < 8; ++j) orow[j * 16 + fr] = acc[i][j][rr] + bias[j];
    }
  }
}

// ---------------------------------------------------------------------------
// Emergency fallback if ws < ~2.2 MB: fused fp32, 1 row/block (slow, correct).
// ---------------------------------------------------------------------------
__global__ __launch_bounds__(256) void k_naive(
    const float* __restrict__ x, const float* __restrict__ ry,
    const float* __restrict__ w1, const float* __restrict__ b1,
    const float* __restrict__ w2, const float* __restrict__ b2,
    float* __restrict__ out) {
  __shared__ float zsh[8];
  __shared__ float acts[2048];
  const int r = blockIdx.x;
  const int t = threadIdx.x;
  if (t < 8) zsh[t] = __cosf(x[(size_t)r * 512 + t]) * __cosf(ry[t]);
  __syncthreads();
  float z[8];
#pragma unroll
  for (int q = 0; q < 8; ++q) z[q] = zsh[q];
#pragma unroll
  for (int i = 0; i < 8; ++i) {
    const int f = t * 8 + i;
    const float* wr = w1 + (size_t)f * 8;
    float4 a = *(const float4*)wr;
    float4 b = *(const float4*)(wr + 4);
    float h = b1[f] + z[0] * a.x + z[1] * a.y + z[2] * a.z + z[3] * a.w +
              z[4] * b.x + z[5] * b.y + z[6] * b.z + z[7] * b.w;
    acts[f] = fmaxf(h, 0.0f);
  }
  __syncthreads();
  for (int ee = 0; ee < 2; ++ee) {
    const int e = t + ee * 256;
    const float* wr = w2 + (size_t)e * 2048;
    float acc = b2[e];
    for (int f = 0; f < 2048; f += 4) {
      float4 wv = *(const float4*)(wr + f);
      float4 av = *(const float4*)(acts + f);
      acc += av.x * wv.x + av.y * wv.y + av.z * wv.z + av.w * wv.w;
    }
    out[(size_t)r * 512 + e] = acc;
  }
}

extern "C" void kernel_launch(void* const* d_in, const int* in_sizes, int n_in,
                              void* d_out, int out_size, void* d_ws,
                              size_t ws_size, hipStream_t stream) {
  const float* x  = (const float*)d_in[0];
  const float* ry = (const float*)d_in[1];
  const float* w1 = (const float*)d_in[2];
  const float* b1 = (const float*)d_in[3];
  const float* w2 = (const float*)d_in[4];
  const float* b2 = (const float*)d_in[5];
  float* out = (float*)d_out;

  const size_t w2t_bytes = (size_t)4 * 64 * 4096 * 2;  // 2 MiB
  const size_t w1t_bytes = (size_t)2048 * 32 * 2;      // 128 KiB
  if (ws_size < w2t_bytes + w1t_bytes) {
    k_naive<<<dim3(16384), dim3(256), 0, stream>>>(x, ry, w1, b1, w2, b2, out);
    return;
  }

  unsigned short* w2t = (unsigned short*)d_ws;
  unsigned short* w1t = (unsigned short*)((char*)d_ws + w2t_bytes);

  k_cvt<<<dim3(136), dim3(256), 0, stream>>>(w2, w1, b1, w2t, w1t);
  k_fused<<<dim3(512), dim3(256), 0, stream>>>(x, ry, w1t, w2t, b2, out);
  (void)in_sizes; (void)n_in; (void)out_size;
}